// Round 5
// baseline (10265.340 us; speedup 1.0000x reference)
//
#include <hip/hip_runtime.h>
#include <math.h>

#define NDIM 4096
#define NR   4095        // rounds = N-1 (rotating positions)
#define NPAIRS 2048      // N/2 tables
#define CB   4           // columns per workgroup slice
#define NTHREADS 256
#define TPT  8           // tables per thread (NPAIRS / NTHREADS)

// Precompute (c, s) per (round, table); bake in the orientation sign:
// table k at round r holds players a=(r+k)%NR (top) and b=(r-k)%NR (bottom,
// or 4095 fixed for k=0). Reference rotates (i,j)=(min,max) with
// U[i]=c*Ui-s*Uj, U[j]=s*Ui+c*Uj. If top==j negate s. top>bottom iff 0<k<=r<NR-k.
__global__ void cs_precompute(const float* __restrict__ thetas,
                              const int* __restrict__ round_theta,
                              float2* __restrict__ cs, int total) {
    int idx = blockIdx.x * blockDim.x + threadIdx.x;
    if (idx >= total) return;
    int r = idx / NPAIRS;
    int k = idx - r * NPAIRS;
    float th = thetas[round_theta[idx]];
    float s, c;
    sincosf(th, &s, &c);
    if (k > 0 && k <= r && r < NR - k) s = -s;
    cs[idx] = make_float2(c, s);
}

// Register-systolic circle method (see round-2 notes for seat algebra).
// Register budget: __launch_bounds__(256,3) -> 512/3 = 170 regs/thread.
// Live state ~130 floats (top/bot 64 + 2x float4[4] cs bufs 32 + temps)
// fits in arch VGPRs -> no AGPR parking -> no accvgpr shuttle instrs.
// (history: (256,2)->80 arch VGPR + AGPR shuttle, 6.6ms; (256,4)->scratch
// spill, 148 GB HBM, 31ms.)
__global__ __launch_bounds__(NTHREADS, 3)
void rotmat_systolic(const float2* __restrict__ cs,
                     float* __restrict__ out) {
    __shared__ float naBuf[2][4][CB];   // lane0 of each wave publishes na(first table)
    __shared__ float nbBuf[2][4][CB];   // lane63 publishes nb(last table)

    const int tid  = threadIdx.x;
    const int lane = tid & 63;
    const int wave = tid >> 6;
    const int col0 = blockIdx.x * CB;

    float top[TPT][CB], bot[TPT][CB];
#pragma unroll
    for (int u = 0; u < TPT; ++u) {
        int g = tid * TPT + u;
        int rowT = g;
        int rowB = (g == 0) ? (NDIM - 1) : (NR - g);
#pragma unroll
        for (int c = 0; c < CB; ++c) {
            top[u][c] = (rowT == col0 + c) ? 1.f : 0.f;
            bot[u][c] = (rowB == col0 + c) ? 1.f : 0.f;
        }
    }
    __syncthreads();

    // cs double buffers: raw float4 (2 tables each), no unpack movs.
    float4 bufA[TPT / 2], bufB[TPT / 2];
    {
        const float4* p = (const float4*)(cs + (size_t)tid * TPT);
#pragma unroll
        for (int q = 0; q < TPT / 2; ++q) bufA[q] = p[q];
    }

    auto do_round = [&](int r, const float4 (&buf)[TPT / 2]) {
        float na0[CB], carry[CB];
#pragma unroll
        for (int u = 0; u < TPT; ++u) {
            const float c_ = (u & 1) ? buf[u >> 1].z : buf[u >> 1].x;
            const float s_ = (u & 1) ? buf[u >> 1].w : buf[u >> 1].y;
            float na[CB], nb[CB];
#pragma unroll
            for (int c = 0; c < CB; ++c) {
                float a = top[u][c], b = bot[u][c];
                na[c] = c_ * a - s_ * b;
                nb[c] = s_ * a + c_ * b;
            }
            if (u == 0) {
#pragma unroll
                for (int c = 0; c < CB; ++c) { na0[c] = na[c]; carry[c] = nb[c]; }
            } else {
#pragma unroll
                for (int c = 0; c < CB; ++c) {
                    top[u - 1][c] = na[c];     // top shifts left
                    bot[u][c]     = carry[c];  // bottom shifts right
                    carry[c]      = nb[c];
                }
            }
        }
        // cross-thread: na(first table) -> prev thread's top[7],
        //               nb(last table)  -> next thread's bot[0]
        float t7[CB], b0[CB];
#pragma unroll
        for (int c = 0; c < CB; ++c) {
            t7[c] = __shfl_down(na0[c], 1);
            b0[c] = __shfl_up(carry[c], 1);
        }
        const int pb = r & 1;
        if (lane == 0) {
#pragma unroll
            for (int c = 0; c < CB; ++c) naBuf[pb][wave][c] = na0[c];
        }
        if (lane == 63) {
#pragma unroll
            for (int c = 0; c < CB; ++c) nbBuf[pb][wave][c] = carry[c];
        }
        __syncthreads();
        if (lane == 63) {
            if (wave < 3) {
#pragma unroll
                for (int c = 0; c < CB; ++c) t7[c] = naBuf[pb][wave + 1][c];
            } else {
                // global thread 255: top[2047] <- own nb(2047)
#pragma unroll
                for (int c = 0; c < CB; ++c) t7[c] = carry[c];
            }
        }
        if (lane == 0 && wave > 0) {
#pragma unroll
            for (int c = 0; c < CB; ++c) b0[c] = nbBuf[pb][wave - 1][c];
        }
#pragma unroll
        for (int c = 0; c < CB; ++c) top[TPT - 1][c] = t7[c];
        if (tid == 0) {
            // fixed seat: bot[0] <- nb(0) (held in bot[1] slot pre-shift);
            // bot[1] <- na(0)
#pragma unroll
            for (int c = 0; c < CB; ++c) { bot[0][c] = bot[1][c]; bot[1][c] = na0[c]; }
        } else {
#pragma unroll
            for (int c = 0; c < CB; ++c) bot[0][c] = b0[c];
        }
    };

    for (int r = 0; r < NR; r += 2) {
        if (r + 1 < NR) {
            const float4* p =
                (const float4*)(cs + (size_t)(r + 1) * NPAIRS + (size_t)tid * TPT);
#pragma unroll
            for (int q = 0; q < TPT / 2; ++q) bufB[q] = p[q];
        }
        do_round(r, bufA);
        if (r + 1 >= NR) break;
        if (r + 2 < NR) {
            const float4* p =
                (const float4*)(cs + (size_t)(r + 2) * NPAIRS + (size_t)tid * TPT);
#pragma unroll
            for (int q = 0; q < TPT / 2; ++q) bufA[q] = p[q];
        }
        do_round(r + 1, bufB);
    }

    // After NR shifts, position q holds player q again.
#pragma unroll
    for (int u = 0; u < TPT; ++u) {
        int g = tid * TPT + u;
        int rowT = g;
        int rowB = (g == 0) ? (NDIM - 1) : (NR - g);
        float4* oT = (float4*)&out[(size_t)rowT * NDIM + col0];
        oT[0] = make_float4(top[u][0], top[u][1], top[u][2], top[u][3]);
        float4* oB = (float4*)&out[(size_t)rowB * NDIM + col0];
        oB[0] = make_float4(bot[u][0], bot[u][1], bot[u][2], bot[u][3]);
    }
}

extern "C" void kernel_launch(void* const* d_in, const int* in_sizes, int n_in,
                              void* d_out, int out_size, void* d_ws, size_t ws_size,
                              hipStream_t stream) {
    const float* thetas      = (const float*)d_in[0];
    const int*   round_theta = (const int*)d_in[3];
    float*       out         = (float*)d_out;

    const int total = NR * NPAIRS;
    float2* cs = (float2*)d_ws;   // 67 MB, verified >= needed in prior rounds

    cs_precompute<<<(total + 255) / 256, 256, 0, stream>>>(
        thetas, round_theta, cs, total);
    rotmat_systolic<<<NDIM / CB, NTHREADS, 0, stream>>>(cs, out);
}

// Round 6
// 7003.259 us; speedup vs baseline: 1.4658x; 1.4658x over previous
//
#include <hip/hip_runtime.h>
#include <math.h>

#define NDIM 4096
#define NR   4095        // rounds = N-1 (rotating positions)
#define NPAIRS 2048      // N/2 tables
#define CB   4           // columns per workgroup slice
#define NTHREADS 512
#define NWAVES (NTHREADS / 64)
#define TPT  4           // tables per thread (NPAIRS / NTHREADS)

// Precompute (c, s) per (round, table); bake in the orientation sign:
// table k at round r holds players a=(r+k)%NR (top) and b=(r-k)%NR (bottom,
// or 4095 fixed for k=0). Reference rotates (i,j)=(min,max) with
// U[i]=c*Ui-s*Uj, U[j]=s*Ui+c*Uj. If top==j negate s. top>bottom iff 0<k<=r<NR-k.
__global__ void cs_precompute(const float* __restrict__ thetas,
                              const int* __restrict__ round_theta,
                              float2* __restrict__ cs, int total) {
    int idx = blockIdx.x * blockDim.x + threadIdx.x;
    if (idx >= total) return;
    int r = idx / NPAIRS;
    int k = idx - r * NPAIRS;
    float th = thetas[round_theta[idx]];
    float s, c;
    sincosf(th, &s, &c);
    if (k > 0 && k <= r && r < NR - k) s = -s;
    cs[idx] = make_float2(c, s);
}

// Register-systolic circle method (round-2 seat algebra, round-4 loop shape).
// 512 thr x TPT=4 x CB=4: per-thread state ~73 floats -> fits the ~80 arch
// VGPRs the allocator picks -> no v_accvgpr shuttle (round-4's overhead) and
// no scratch spill (round-3's failure). History:
//   r2: CB=8,256thr,(256,2): 6.4ms, state~200, AGPR shuttle
//   r3: CB=4,256thr,(256,4): 31ms, forced 128-reg cap -> 148GB scratch
//   r4: CB=4,256thr,(256,2): 6.6ms, 80 VGPR + ~45 parked -> shuttle
//   r5: lambda/unroll2 restructure: 10.3ms, VALU time halved but stalls 7x
__global__ __launch_bounds__(NTHREADS, 2)
void rotmat_systolic(const float2* __restrict__ cs,
                     float* __restrict__ out) {
    __shared__ float naBuf[2][NWAVES][CB];  // lane0 of each wave: na(first table)
    __shared__ float nbBuf[2][NWAVES][CB];  // lane63 of each wave: nb(last table)

    const int tid  = threadIdx.x;
    const int lane = tid & 63;
    const int wave = tid >> 6;
    const int col0 = blockIdx.x * CB;

    float top[TPT][CB], bot[TPT][CB];
    // round 0: position q holds player q
#pragma unroll
    for (int u = 0; u < TPT; ++u) {
        int g = tid * TPT + u;
        int rowT = g;
        int rowB = (g == 0) ? (NDIM - 1) : (NR - g);
#pragma unroll
        for (int c = 0; c < CB; ++c) {
            top[u][c] = (rowT == col0 + c) ? 1.f : 0.f;
            bot[u][c] = (rowB == col0 + c) ? 1.f : 0.f;
        }
    }

    float2 csCur[TPT], csNext[TPT];
    {
        const float4* p = (const float4*)(cs + (size_t)tid * TPT);
#pragma unroll
        for (int q = 0; q < TPT / 2; ++q) {
            float4 v = p[q];
            csCur[2 * q]     = make_float2(v.x, v.y);
            csCur[2 * q + 1] = make_float2(v.z, v.w);
        }
    }

    for (int r = 0; r < NR; ++r) {
        if (r + 1 < NR) {
            const float4* p =
                (const float4*)(cs + (size_t)(r + 1) * NPAIRS + (size_t)tid * TPT);
#pragma unroll
            for (int q = 0; q < TPT / 2; ++q) {
                float4 v = p[q];
                csNext[2 * q]     = make_float2(v.x, v.y);
                csNext[2 * q + 1] = make_float2(v.z, v.w);
            }
        }

        float na0[CB], carry[CB];
#pragma unroll
        for (int u = 0; u < TPT; ++u) {
            const float c_ = csCur[u].x;
            const float s_ = csCur[u].y;
            float na[CB], nb[CB];
#pragma unroll
            for (int c = 0; c < CB; ++c) {
                float a = top[u][c], b = bot[u][c];
                na[c] = c_ * a - s_ * b;
                nb[c] = s_ * a + c_ * b;
            }
            if (u == 0) {
#pragma unroll
                for (int c = 0; c < CB; ++c) { na0[c] = na[c]; carry[c] = nb[c]; }
            } else {
#pragma unroll
                for (int c = 0; c < CB; ++c) {
                    top[u - 1][c] = na[c];     // top shifts left
                    bot[u][c]     = carry[c];  // bottom shifts right
                    carry[c]      = nb[c];
                }
            }
        }
        // cross-thread: na(first table) -> prev thread's top[TPT-1],
        //               nb(last table)  -> next thread's bot[0]
        float t7[CB], b0[CB];
#pragma unroll
        for (int c = 0; c < CB; ++c) {
            t7[c] = __shfl_down(na0[c], 1);
            b0[c] = __shfl_up(carry[c], 1);
        }
        const int pb = r & 1;
        if (lane == 0) {
#pragma unroll
            for (int c = 0; c < CB; ++c) naBuf[pb][wave][c] = na0[c];
        }
        if (lane == 63) {
#pragma unroll
            for (int c = 0; c < CB; ++c) nbBuf[pb][wave][c] = carry[c];
        }
        __syncthreads();
        if (lane == 63) {
            if (wave < NWAVES - 1) {
#pragma unroll
                for (int c = 0; c < CB; ++c) t7[c] = naBuf[pb][wave + 1][c];
            } else {
                // last thread: top[NPAIRS-1] <- own nb(NPAIRS-1)
#pragma unroll
                for (int c = 0; c < CB; ++c) t7[c] = carry[c];
            }
        }
        if (lane == 0 && wave > 0) {
#pragma unroll
            for (int c = 0; c < CB; ++c) b0[c] = nbBuf[pb][wave - 1][c];
        }
#pragma unroll
        for (int c = 0; c < CB; ++c) top[TPT - 1][c] = t7[c];
        if (tid == 0) {
            // fixed seat: bot[0] <- nb(0) (currently in bot[1] slot);
            // bot[1] <- na(0)
#pragma unroll
            for (int c = 0; c < CB; ++c) { bot[0][c] = bot[1][c]; bot[1][c] = na0[c]; }
        } else {
#pragma unroll
            for (int c = 0; c < CB; ++c) bot[0][c] = b0[c];
        }
#pragma unroll
        for (int u = 0; u < TPT; ++u) csCur[u] = csNext[u];
    }

    // After NR shifts, position q holds player q again.
#pragma unroll
    for (int u = 0; u < TPT; ++u) {
        int g = tid * TPT + u;
        int rowT = g;
        int rowB = (g == 0) ? (NDIM - 1) : (NR - g);
        float4* oT = (float4*)&out[(size_t)rowT * NDIM + col0];
        oT[0] = make_float4(top[u][0], top[u][1], top[u][2], top[u][3]);
        float4* oB = (float4*)&out[(size_t)rowB * NDIM + col0];
        oB[0] = make_float4(bot[u][0], bot[u][1], bot[u][2], bot[u][3]);
    }
}

extern "C" void kernel_launch(void* const* d_in, const int* in_sizes, int n_in,
                              void* d_out, int out_size, void* d_ws, size_t ws_size,
                              hipStream_t stream) {
    const float* thetas      = (const float*)d_in[0];
    const int*   round_theta = (const int*)d_in[3];
    float*       out         = (float*)d_out;

    const int total = NR * NPAIRS;
    float2* cs = (float2*)d_ws;   // 67 MB workspace (verified sufficient)

    cs_precompute<<<(total + 255) / 256, 256, 0, stream>>>(
        thetas, round_theta, cs, total);
    rotmat_systolic<<<NDIM / CB, NTHREADS, 0, stream>>>(cs, out);
}

// Round 7
// 6241.707 us; speedup vs baseline: 1.6446x; 1.1220x over previous
//
#include <hip/hip_runtime.h>
#include <math.h>

#define NDIM 4096
#define NR   4095        // rounds = N-1 (rotating positions)
#define NPAIRS 2048      // N/2 tables
#define CB   4           // columns per workgroup slice
#define NTHREADS 512
#define NWAVES (NTHREADS / 64)
#define TPT  4           // tables per thread (NPAIRS / NTHREADS)

// Precompute (c, s) per (round, table); bake in the orientation sign:
// table k at round r holds players a=(r+k)%NR (top) and b=(r-k)%NR (bottom,
// or 4095 fixed for k=0). Reference rotates (i,j)=(min,max) with
// U[i]=c*Ui-s*Uj, U[j]=s*Ui+c*Uj. If top==j negate s. top>bottom iff 0<k<=r<NR-k.
__global__ void cs_precompute(const float* __restrict__ thetas,
                              const int* __restrict__ round_theta,
                              float2* __restrict__ cs, int total) {
    int idx = blockIdx.x * blockDim.x + threadIdx.x;
    if (idx >= total) return;
    int r = idx / NPAIRS;
    int k = idx - r * NPAIRS;
    float th = thetas[round_theta[idx]];
    float s, c;
    sincosf(th, &s, &c);
    if (k > 0 && k <= r && r < NR - k) s = -s;
    cs[idx] = make_float2(c, s);
}

// Register-systolic circle method, phase-rotated in-place update.
// At phase p (= round mod 4): logical top[u] lives in T[(u+p)&3],
// logical bot[u] in B[(u-p)&3]. Then the per-round ring shift
// (top[u-1]<-na[u], bot[u]<-nb[u-1]) becomes a pure RENAME: each table's
// na/nb write back into the very slots its a/b were read from. Zero
// loop-carried permutation moves. Boundary traffic (na of first table,
// nb of last table) via shfl +/-1 lane and a tiny LDS ping-pong.
// asm "+v" pins force top/bot into arch VGPRs (history: allocator parked
// them in AGPRs -> 64 v_accvgpr shuttles/round = 2.5x instr bloat;
// r6: VGPR_Count=44, 226 instr/thread/round vs ~90 useful).
#define PIN16(A)                                                        \
    asm volatile("" : "+v"(A[0][0]), "+v"(A[0][1]), "+v"(A[0][2]),      \
                      "+v"(A[0][3]), "+v"(A[1][0]), "+v"(A[1][1]),      \
                      "+v"(A[1][2]), "+v"(A[1][3]), "+v"(A[2][0]),      \
                      "+v"(A[2][1]), "+v"(A[2][2]), "+v"(A[2][3]),      \
                      "+v"(A[3][0]), "+v"(A[3][1]), "+v"(A[3][2]),      \
                      "+v"(A[3][3]))

// One round at compile-time phase P. BUFC = this round's cs (float4[2]);
// BUFP = prefetch target (round RND+2); DO_PF = issue prefetch.
#define PHASE(P, RND, BUFC, BUFP, DO_PF)                                      \
  {                                                                           \
    if (DO_PF) {                                                              \
      const float4* pf = csp + (size_t)((RND) + 2) * (NPAIRS / 2);            \
      BUFP[0] = pf[0]; BUFP[1] = pf[1];                                       \
    }                                                                         \
    PIN16(T); PIN16(B);                                                       \
    float na0[CB], nb0[CB], nbL[CB];                                          \
    { /* u=0: na exported, nb deferred */                                     \
      const float c_ = BUFC[0].x, s_ = BUFC[0].y;                             \
      _Pragma("unroll") for (int c = 0; c < CB; ++c) {                        \
        float a = T[(0 + P) & 3][c], b = B[(0 - P + 4) & 3][c];               \
        na0[c] = c_ * a - s_ * b;                                             \
        nb0[c] = s_ * a + c_ * b; } }                                         \
    { /* u=1: in place */                                                     \
      const float c_ = BUFC[0].z, s_ = BUFC[0].w;                             \
      _Pragma("unroll") for (int c = 0; c < CB; ++c) {                        \
        float a = T[(1 + P) & 3][c], b = B[(1 - P + 4) & 3][c];               \
        T[(1 + P) & 3][c] = c_ * a - s_ * b;                                  \
        B[(1 - P + 4) & 3][c] = s_ * a + c_ * b; } }                          \
    { /* u=2: in place */                                                     \
      const float c_ = BUFC[1].x, s_ = BUFC[1].y;                             \
      _Pragma("unroll") for (int c = 0; c < CB; ++c) {                        \
        float a = T[(2 + P) & 3][c], b = B[(2 - P + 4) & 3][c];               \
        T[(2 + P) & 3][c] = c_ * a - s_ * b;                                  \
        B[(2 - P + 4) & 3][c] = s_ * a + c_ * b; } }                          \
    { /* u=3: na in place, nb exported */                                     \
      const float c_ = BUFC[1].z, s_ = BUFC[1].w;                             \
      _Pragma("unroll") for (int c = 0; c < CB; ++c) {                        \
        float a = T[(3 + P) & 3][c], b = B[(3 - P + 4) & 3][c];               \
        T[(3 + P) & 3][c] = c_ * a - s_ * b;                                  \
        nbL[c] = s_ * a + c_ * b; } }                                         \
    float t7[CB], bi[CB];                                                     \
    _Pragma("unroll") for (int c = 0; c < CB; ++c) {                          \
      t7[c] = __shfl_down(na0[c], 1);                                         \
      bi[c] = __shfl_up(nbL[c], 1); }                                         \
    if (lane == 0) { _Pragma("unroll") for (int c = 0; c < CB; ++c)           \
        naBuf[(P) & 1][wave][c] = na0[c]; }                                   \
    if (lane == 63) { _Pragma("unroll") for (int c = 0; c < CB; ++c)          \
        nbBuf[(P) & 1][wave][c] = nbL[c]; }                                   \
    __syncthreads();                                                          \
    if (lane == 63) {                                                         \
      if (wave < NWAVES - 1) { _Pragma("unroll")                              \
        for (int c = 0; c < CB; ++c) t7[c] = naBuf[(P) & 1][wave + 1][c]; }   \
      else { _Pragma("unroll")                                                \
        for (int c = 0; c < CB; ++c) t7[c] = nbL[c]; } }                      \
    if (lane == 0 && wave > 0) { _Pragma("unroll")                            \
      for (int c = 0; c < CB; ++c) bi[c] = nbBuf[(P) & 1][wave - 1][c]; }     \
    _Pragma("unroll") for (int c = 0; c < CB; ++c) {                          \
      T[(P) & 3][c] = t7[c];                       /* top import slot */      \
      B[(0 - P + 4) & 3][c] = (tid == 0) ? na0[c] : nb0[c];                   \
      B[(3 - P + 4) & 3][c] = (tid == 0) ? nb0[c] : bi[c];                    \
    }                                                                         \
  }

__global__ __launch_bounds__(NTHREADS, 2)
void rotmat_systolic(const float2* __restrict__ cs,
                     float* __restrict__ out) {
    __shared__ float naBuf[2][NWAVES][CB];
    __shared__ float nbBuf[2][NWAVES][CB];

    const int tid  = threadIdx.x;
    const int lane = tid & 63;
    const int wave = tid >> 6;
    const int col0 = blockIdx.x * CB;

    float T[TPT][CB], B[TPT][CB];
    // phase 0: logical top[u] -> T[u] (row g), bot[u] -> B[u] (row 4095-g)
#pragma unroll
    for (int u = 0; u < TPT; ++u) {
        int g = tid * TPT + u;
        int rowB = NR - g;            // g=0 -> 4095 (fixed player) too
#pragma unroll
        for (int c = 0; c < CB; ++c) {
            T[u][c] = (g == col0 + c) ? 1.f : 0.f;
            B[u][c] = (rowB == col0 + c) ? 1.f : 0.f;
        }
    }

    const float4* csp = (const float4*)(cs + (size_t)tid * TPT);
    float4 csb0[2], csb1[2], csb2[2], csb3[2];
    csb0[0] = csp[0]; csb0[1] = csp[1];                          // round 0
    { const float4* p = csp + (size_t)1 * (NPAIRS / 2);          // round 1
      csb1[0] = p[0]; csb1[1] = p[1]; }

    int r = 0;
    for (int it = 0; it < 1023; ++it, r += 4) {   // rounds 0..4091
        PHASE(0, r,     csb0, csb2, 1)            // pf r+2 -> csb2
        PHASE(1, r + 1, csb1, csb3, 1)            // pf r+3 -> csb3
        PHASE(2, r + 2, csb2, csb0, 1)            // pf r+4 -> csb0
        PHASE(3, r + 3, csb3, csb1, 1)            // pf r+5 -> csb1
    }
    // tail: rounds 4092 (phase0), 4093 (phase1), 4094 (phase2)
    PHASE(0, r,     csb0, csb2, 1)                // pf 4094 -> csb2
    PHASE(1, r + 1, csb1, csb3, 0)
    PHASE(2, r + 2, csb2, csb0, 0)

    // final phase index Q = NR mod 4 = 3:
    // logical top[u] -> T[(u+3)&3], bot[u] -> B[(u-3)&3] = B[(u+1)&3]
#pragma unroll
    for (int u = 0; u < TPT; ++u) {
        int g = tid * TPT + u;
        int rowB = NR - g;
        float* Tp = T[(u + 3) & 3];
        float* Bp = B[(u + 1) & 3];
        float4* oT = (float4*)&out[(size_t)g * NDIM + col0];
        oT[0] = make_float4(Tp[0], Tp[1], Tp[2], Tp[3]);
        float4* oB = (float4*)&out[(size_t)rowB * NDIM + col0];
        oB[0] = make_float4(Bp[0], Bp[1], Bp[2], Bp[3]);
    }
}

extern "C" void kernel_launch(void* const* d_in, const int* in_sizes, int n_in,
                              void* d_out, int out_size, void* d_ws, size_t ws_size,
                              hipStream_t stream) {
    const float* thetas      = (const float*)d_in[0];
    const int*   round_theta = (const int*)d_in[3];
    float*       out         = (float*)d_out;

    const int total = NR * NPAIRS;
    float2* cs = (float2*)d_ws;   // 67 MB workspace (verified sufficient)

    cs_precompute<<<(total + 255) / 256, 256, 0, stream>>>(
        thetas, round_theta, cs, total);
    rotmat_systolic<<<NDIM / CB, NTHREADS, 0, stream>>>(cs, out);
}